// Round 2
// baseline (9194.387 us; speedup 1.0000x reference)
//
#include <hip/hip_runtime.h>
#include <hip/hip_bf16.h>
#include <cstdint>
#include <type_traits>

#define N_NODES 100000
#define N_EDGES 500000
#define FEAT 128
#define HID 256
#define N_LINKS 16384

// ---- generic scalar load/store (fp32 or bf16 h-storage) ----
__device__ __forceinline__ float ldf(const float* p) { return *p; }
__device__ __forceinline__ float ldf(const __hip_bfloat16* p) { return __bfloat162float(*p); }
__device__ __forceinline__ void stf(float* p, float v) { *p = v; }
__device__ __forceinline__ void stf(__hip_bfloat16* p, float v) { *p = __float2bfloat16(v); }

// defensive: any out-of-range index becomes 0 (wrong answer, not a fault)
__device__ __forceinline__ int clampi(int v, int n) { return ((unsigned)v < (unsigned)n) ? v : 0; }

// ---------------- small utility kernels ----------------

__global__ void zero_f32(float* p, int n) {
    int i = blockIdx.x * blockDim.x + threadIdx.x;
    if (i < n) p[i] = 0.0f;
}

__global__ void deg_kernel(const int* __restrict__ dst, float* __restrict__ deg, int nE) {
    int e = blockIdx.x * blockDim.x + threadIdx.x;
    if (e < nE) atomicAdd(&deg[clampi(dst[e], N_NODES)], 1.0f);
}

// agg[i] = (float)h[i]   (self-loop seed)
template <typename TH>
__global__ void seed_agg(const TH* __restrict__ h, float* __restrict__ agg, long long n) {
    long long i = (long long)blockIdx.x * blockDim.x + threadIdx.x;
    if (i < n) agg[i] = ldf(&h[i]);
}

// scatter-add h[src] rows into agg[dst] rows; one thread per (edge, 4-col group)
template <typename TH>
__global__ void scatter_kernel(const TH* __restrict__ h,
                               const int* __restrict__ src,
                               const int* __restrict__ dst,
                               float* __restrict__ agg, int nE) {
    long long idx = (long long)blockIdx.x * blockDim.x + threadIdx.x;
    if (idx >= (long long)nE * (HID / 4)) return;
    int e  = (int)(idx >> 6);        // HID/4 == 64
    int c4 = (int)(idx & 63);
    int s = clampi(src[e], N_NODES);
    int d = clampi(dst[e], N_NODES);
    const TH* hp = &h[(long long)s * HID + c4 * 4];
    float* base  = &agg[(long long)d * HID + c4 * 4];
    if constexpr (std::is_same<TH, float>::value) {
        const float4 v = *(const float4*)hp;
        atomicAdd(base + 0, v.x);
        atomicAdd(base + 1, v.y);
        atomicAdd(base + 2, v.z);
        atomicAdd(base + 3, v.w);
    } else {
        #pragma unroll
        for (int j = 0; j < 4; j++) atomicAdd(base + j, ldf(hp + j));
    }
}

// agg[n, :] /= (deg[n] + 1)
__global__ void mean_kernel(float* __restrict__ agg, const float* __restrict__ deg, int nNodes) {
    long long idx = (long long)blockIdx.x * blockDim.x + threadIdx.x;
    if (idx >= (long long)nNodes * (HID / 4)) return;
    int n = (int)(idx >> 6);
    float inv = 1.0f / (deg[n] + 1.0f);
    float4* p = (float4*)&agg[idx * 4];
    float4 v = *p;
    v.x *= inv; v.y *= inv; v.z *= inv; v.w *= inv;
    *p = v;
}

// ---------------- embedding GEMM: C[M,N] = A[M,K] @ B[N,K]^T + bias ----------------
// BM=64, BN=64, BK=16, 256 threads, 4x4 micro-tile per thread.

template <typename TC>
__global__ __launch_bounds__(256) void gemm_emb(const float* __restrict__ A,
                                                const float* __restrict__ B,
                                                const float* __restrict__ bias,
                                                TC* __restrict__ C,
                                                int M, int N, int K) {
    const int BK = 16;
    __shared__ float As[64][BK + 1];
    __shared__ float Bs[64][BK + 1];
    int tid = threadIdx.x;
    int bn = blockIdx.x, bm = blockIdx.y;
    int tx = tid & 15, ty = tid >> 4;
    int row0 = bm * 64, col0 = bn * 64;

    float acc[4][4] = {};

    for (int k0 = 0; k0 < K; k0 += BK) {
        int r = tid >> 2;            // 0..63
        int c = (tid & 3) * 4;       // 0,4,8,12
        {
            int gr = row0 + r;
            float4 v = make_float4(0.f, 0.f, 0.f, 0.f);
            if (gr < M) v = *(const float4*)&A[(long long)gr * K + k0 + c];
            As[r][c] = v.x; As[r][c + 1] = v.y; As[r][c + 2] = v.z; As[r][c + 3] = v.w;
        }
        {
            int gc = col0 + r;
            float4 w = make_float4(0.f, 0.f, 0.f, 0.f);
            if (gc < N) w = *(const float4*)&B[(long long)gc * K + k0 + c];
            Bs[r][c] = w.x; Bs[r][c + 1] = w.y; Bs[r][c + 2] = w.z; Bs[r][c + 3] = w.w;
        }
        __syncthreads();
        #pragma unroll
        for (int kk = 0; kk < BK; ++kk) {
            float a[4], b[4];
            #pragma unroll
            for (int i = 0; i < 4; i++) a[i] = As[ty * 4 + i][kk];
            #pragma unroll
            for (int j = 0; j < 4; j++) b[j] = Bs[tx * 4 + j][kk];
            #pragma unroll
            for (int i = 0; i < 4; i++)
                #pragma unroll
                for (int j = 0; j < 4; j++)
                    acc[i][j] += a[i] * b[j];
        }
        __syncthreads();
    }

    #pragma unroll
    for (int i = 0; i < 4; i++) {
        int r = row0 + ty * 4 + i;
        if (r >= M) continue;
        #pragma unroll
        for (int j = 0; j < 4; j++) {
            int c = col0 + tx * 4 + j;
            if (c >= N) continue;
            stf(&C[(long long)r * N + c], acc[i][j] + bias[c]);
        }
    }
}

// ---------------- fused SAGE layer GEMM ----------------
// C[M,HID] = relu( A1@B1^T + bias + A2@B2^T ),  A1 = mean (fp32), A2 = h (TH)
// K = N = HID = 256.

template <typename TH>
__global__ __launch_bounds__(256) void gemm_layer(const float* __restrict__ A1,
                                                  const TH* __restrict__ A2,
                                                  const float* __restrict__ B1,
                                                  const float* __restrict__ B2,
                                                  const float* __restrict__ bias,
                                                  TH* __restrict__ C, int M) {
    const int K = HID, N = HID, BK = 16;
    __shared__ float As1[64][BK + 1];
    __shared__ float As2[64][BK + 1];
    __shared__ float Bs1[64][BK + 1];
    __shared__ float Bs2[64][BK + 1];
    int tid = threadIdx.x;
    int bn = blockIdx.x, bm = blockIdx.y;
    int tx = tid & 15, ty = tid >> 4;
    int row0 = bm * 64, col0 = bn * 64;

    float acc[4][4] = {};

    for (int k0 = 0; k0 < K; k0 += BK) {
        int r = tid >> 2;
        int c = (tid & 3) * 4;
        int gr = row0 + r;
        if (gr < M) {
            const float4 v = *(const float4*)&A1[(long long)gr * K + k0 + c];
            As1[r][c] = v.x; As1[r][c + 1] = v.y; As1[r][c + 2] = v.z; As1[r][c + 3] = v.w;
            const TH* hp = &A2[(long long)gr * K + k0 + c];
            if constexpr (std::is_same<TH, float>::value) {
                const float4 w = *(const float4*)hp;
                As2[r][c] = w.x; As2[r][c + 1] = w.y; As2[r][c + 2] = w.z; As2[r][c + 3] = w.w;
            } else {
                #pragma unroll
                for (int j = 0; j < 4; j++) As2[r][c + j] = ldf(hp + j);
            }
        } else {
            #pragma unroll
            for (int j = 0; j < 4; j++) { As1[r][c + j] = 0.f; As2[r][c + j] = 0.f; }
        }
        {
            int gc = col0 + r;   // always < N here (N=256, grid.x=4)
            const float4 b1 = *(const float4*)&B1[(long long)gc * K + k0 + c];
            Bs1[r][c] = b1.x; Bs1[r][c + 1] = b1.y; Bs1[r][c + 2] = b1.z; Bs1[r][c + 3] = b1.w;
            const float4 b2 = *(const float4*)&B2[(long long)gc * K + k0 + c];
            Bs2[r][c] = b2.x; Bs2[r][c + 1] = b2.y; Bs2[r][c + 2] = b2.z; Bs2[r][c + 3] = b2.w;
        }
        __syncthreads();
        #pragma unroll
        for (int kk = 0; kk < BK; ++kk) {
            float a1[4], a2[4], b1v[4], b2v[4];
            #pragma unroll
            for (int i = 0; i < 4; i++) { a1[i] = As1[ty * 4 + i][kk]; a2[i] = As2[ty * 4 + i][kk]; }
            #pragma unroll
            for (int j = 0; j < 4; j++) { b1v[j] = Bs1[tx * 4 + j][kk]; b2v[j] = Bs2[tx * 4 + j][kk]; }
            #pragma unroll
            for (int i = 0; i < 4; i++)
                #pragma unroll
                for (int j = 0; j < 4; j++)
                    acc[i][j] += a1[i] * b1v[j] + a2[i] * b2v[j];
        }
        __syncthreads();
    }

    #pragma unroll
    for (int i = 0; i < 4; i++) {
        int r = row0 + ty * 4 + i;
        if (r >= M) continue;
        #pragma unroll
        for (int j = 0; j < 4; j++) {
            int c = col0 + tx * 4 + j;
            float v = fmaxf(acc[i][j] + bias[c], 0.0f);
            stf(&C[(long long)r * N + c], v);
        }
    }
}

// ---------------- fused prediction head ----------------

template <typename TH>
__global__ __launch_bounds__(256) void pred_kernel(const TH* __restrict__ h,
                                                   const int* __restrict__ src_idx,
                                                   const int* __restrict__ dst_idx,
                                                   const float* __restrict__ wp1,
                                                   const float* __restrict__ bp1,
                                                   const float* __restrict__ wp2,
                                                   const float* __restrict__ bp2,
                                                   float* __restrict__ out) {
    int row = blockIdx.x;
    int t = threadIdx.x;
    __shared__ float comb[4 * HID];
    __shared__ float red[256];

    int s = clampi(src_idx[row], N_NODES);
    int d = clampi(dst_idx[row], N_NODES);
    float sv = ldf(&h[(long long)s * HID + t]);
    float dv = ldf(&h[(long long)d * HID + t]);
    comb[t]           = sv;
    comb[HID + t]     = dv;
    comb[2 * HID + t] = sv * dv;
    comb[3 * HID + t] = fabsf(sv - dv);
    __syncthreads();

    const float* wrow = &wp1[(long long)t * (4 * HID)];
    float accv = bp1[t];
    #pragma unroll 4
    for (int k = 0; k < 4 * HID; k++) accv += comb[k] * wrow[k];
    accv = fmaxf(accv, 0.0f);

    red[t] = accv * wp2[t];
    __syncthreads();
    for (int s2 = 128; s2 > 0; s2 >>= 1) {
        if (t < s2) red[t] += red[t + s2];
        __syncthreads();
    }
    if (t == 0) out[row] = 1.0f / (1.0f + expf(-(red[0] + bp2[0])));
}

// ---------------- pipeline (templated on h-storage type) ----------------

template <typename TH>
static void run_pipeline(const float* x, const int* e_src, const int* e_dst,
                         const int* src_idx, const int* dst_idx,
                         const float* w_emb, const float* b_emb,
                         const float* wl0, const float* bl0, const float* wr0,
                         const float* wl1, const float* bl1, const float* wr1,
                         const float* wp1, const float* bp1,
                         const float* wp2, const float* bp2,
                         float* out, char* ws, hipStream_t stream) {
    const long long NH = (long long)N_NODES * HID;
    float* agg = (float*)ws;                       // NH fp32
    TH*    h0  = (TH*)(ws + NH * sizeof(float));   // NH TH
    TH*    h1  = h0 + NH;                          // NH TH
    float* deg = (float*)((char*)(h1 + NH));       // N_NODES fp32

    const int seedBlk = (int)((NH + 255) / 256);
    const long long scTot = (long long)N_EDGES * (HID / 4);
    const int scBlk = (int)((scTot + 255) / 256);
    const int mBlk = (int)(((long long)N_NODES * (HID / 4) + 255) / 256);
    dim3 ggrid(HID / 64, (N_NODES + 63) / 64);

    zero_f32<<<(N_NODES + 255) / 256, 256, 0, stream>>>(deg, N_NODES);
    deg_kernel<<<(N_EDGES + 255) / 256, 256, 0, stream>>>(e_dst, deg, N_EDGES);

    gemm_emb<TH><<<ggrid, 256, 0, stream>>>(x, w_emb, b_emb, h0, N_NODES, HID, FEAT);

    // layer 0: h1 = relu(mean(h0) @ wl0^T + bl0 + h0 @ wr0^T)
    seed_agg<TH><<<seedBlk, 256, 0, stream>>>(h0, agg, NH);
    scatter_kernel<TH><<<scBlk, 256, 0, stream>>>(h0, e_src, e_dst, agg, N_EDGES);
    mean_kernel<<<mBlk, 256, 0, stream>>>(agg, deg, N_NODES);
    gemm_layer<TH><<<ggrid, 256, 0, stream>>>(agg, h0, wl0, wr0, bl0, h1, N_NODES);

    // layer 1: h0 = relu(mean(h1) @ wl1^T + bl1 + h1 @ wr1^T)
    seed_agg<TH><<<seedBlk, 256, 0, stream>>>(h1, agg, NH);
    scatter_kernel<TH><<<scBlk, 256, 0, stream>>>(h1, e_src, e_dst, agg, N_EDGES);
    mean_kernel<<<mBlk, 256, 0, stream>>>(agg, deg, N_NODES);
    gemm_layer<TH><<<ggrid, 256, 0, stream>>>(agg, h1, wl1, wr1, bl1, h0, N_NODES);

    pred_kernel<TH><<<N_LINKS, 256, 0, stream>>>(h0, src_idx, dst_idx, wp1, bp1, wp2, bp2, out);
}

// ---------------- launch ----------------

extern "C" void kernel_launch(void* const* d_in, const int* in_sizes, int n_in,
                              void* d_out, int out_size, void* d_ws, size_t ws_size,
                              hipStream_t stream) {
    const float* x          = (const float*)d_in[0];
    const int*   edge_index = (const int*)d_in[1];
    const int*   e_src      = edge_index;            // row 0
    const int*   e_dst      = edge_index + N_EDGES;  // row 1
    const int*   src_idx    = (const int*)d_in[3];
    const int*   dst_idx    = (const int*)d_in[4];
    const float* w_emb      = (const float*)d_in[5];
    const float* b_emb      = (const float*)d_in[6];
    const float* wl0        = (const float*)d_in[8];
    const float* bl0        = (const float*)d_in[9];
    const float* wr0        = (const float*)d_in[10];
    const float* wl1        = (const float*)d_in[13];
    const float* bl1        = (const float*)d_in[14];
    const float* wr1        = (const float*)d_in[15];
    const float* wp1        = (const float*)d_in[18];
    const float* bp1        = (const float*)d_in[19];
    const float* wp2        = (const float*)d_in[20];
    const float* bp2        = (const float*)d_in[21];
    float* out = (float*)d_out;

    const size_t NH = (size_t)N_NODES * HID;
    const size_t need_f32  = NH * 4 + 2 * NH * 4 + (size_t)N_NODES * 4;  // agg + 2 fp32 h + deg
    const size_t need_bf16 = NH * 4 + 2 * NH * 2 + (size_t)N_NODES * 4;  // agg + 2 bf16 h + deg

    if (ws_size >= need_f32) {
        run_pipeline<float>(x, e_src, e_dst, src_idx, dst_idx, w_emb, b_emb,
                            wl0, bl0, wr0, wl1, bl1, wr1, wp1, bp1, wp2, bp2,
                            out, (char*)d_ws, stream);
    } else if (ws_size >= need_bf16) {
        run_pipeline<__hip_bfloat16>(x, e_src, e_dst, src_idx, dst_idx, w_emb, b_emb,
                                     wl0, bl0, wr0, wl1, bl1, wr1, wp1, bp1, wp2, bp2,
                                     out, (char*)d_ws, stream);
    } else {
        // workspace too small for any valid plan — emit zeros (visible failure, no fault)
        zero_f32<<<(out_size + 255) / 256, 256, 0, stream>>>(out, out_size);
    }
}

// Round 3
// 5538.329 us; speedup vs baseline: 1.6601x; 1.6601x over previous
//
#include <hip/hip_runtime.h>
#include <hip/hip_bf16.h>
#include <cstdint>
#include <type_traits>

#define N_NODES 100000
#define N_EDGES 500000
#define FEAT 128
#define HID 256
#define N_LINKS 16384

// ---- generic scalar load/store (fp32 or bf16 h-storage) ----
__device__ __forceinline__ float ldf(const float* p) { return *p; }
__device__ __forceinline__ float ldf(const __hip_bfloat16* p) { return __bfloat162float(*p); }
__device__ __forceinline__ void stf(float* p, float v) { *p = v; }
__device__ __forceinline__ void stf(__hip_bfloat16* p, float v) { *p = __float2bfloat16(v); }

// defensive: any out-of-range index becomes 0 (wrong answer, not a fault)
__device__ __forceinline__ int clampi(int v, int n) { return ((unsigned)v < (unsigned)n) ? v : 0; }

// ---------------- small utility kernels ----------------

__global__ void zero_f32(float* p, int n) {
    int i = blockIdx.x * blockDim.x + threadIdx.x;
    if (i < n) p[i] = 0.0f;
}

__global__ void deg_kernel(const int* __restrict__ dst, float* __restrict__ deg, int nE) {
    int e = blockIdx.x * blockDim.x + threadIdx.x;
    if (e < nE) atomicAdd(&deg[clampi(dst[e], N_NODES)], 1.0f);
}

// agg[i] = (float)h[i]   (self-loop seed)
template <typename TH>
__global__ void seed_agg(const TH* __restrict__ h, float* __restrict__ agg, long long n) {
    long long i = (long long)blockIdx.x * blockDim.x + threadIdx.x;
    if (i < n) agg[i] = ldf(&h[i]);
}

// scatter-add h[src] rows into agg[dst] rows; one thread per (edge, 4-col group)
template <typename TH>
__global__ void scatter_kernel(const TH* __restrict__ h,
                               const int* __restrict__ src,
                               const int* __restrict__ dst,
                               float* __restrict__ agg, int nE) {
    long long idx = (long long)blockIdx.x * blockDim.x + threadIdx.x;
    if (idx >= (long long)nE * (HID / 4)) return;
    int e  = (int)(idx >> 6);        // HID/4 == 64
    int c4 = (int)(idx & 63);
    int s = clampi(src[e], N_NODES);
    int d = clampi(dst[e], N_NODES);
    const TH* hp = &h[(long long)s * HID + c4 * 4];
    float* base  = &agg[(long long)d * HID + c4 * 4];
    if constexpr (std::is_same<TH, float>::value) {
        const float4 v = *(const float4*)hp;
        atomicAdd(base + 0, v.x);
        atomicAdd(base + 1, v.y);
        atomicAdd(base + 2, v.z);
        atomicAdd(base + 3, v.w);
    } else {
        #pragma unroll
        for (int j = 0; j < 4; j++) atomicAdd(base + j, ldf(hp + j));
    }
}

// agg[n, :] /= (deg[n] + 1)
__global__ void mean_kernel(float* __restrict__ agg, const float* __restrict__ deg, int nNodes) {
    long long idx = (long long)blockIdx.x * blockDim.x + threadIdx.x;
    if (idx >= (long long)nNodes * (HID / 4)) return;
    int n = (int)(idx >> 6);
    float inv = 1.0f / (deg[n] + 1.0f);
    float4* p = (float4*)&agg[idx * 4];
    float4 v = *p;
    v.x *= inv; v.y *= inv; v.z *= inv; v.w *= inv;
    *p = v;
}

// ---------------- generic tiled GEMM: C[M,N] = (relu)(A[M,K] @ B[N,K]^T + bias) ----
// BM=64, BN=64, BK=16, 256 threads, 4x4 micro-tile per thread.

template <typename TC, bool RELU>
__global__ __launch_bounds__(256) void gemm_bt(const float* __restrict__ A,
                                               const float* __restrict__ B,
                                               const float* __restrict__ bias,
                                               TC* __restrict__ C,
                                               int M, int N, int K) {
    const int BK = 16;
    __shared__ float As[64][BK + 1];
    __shared__ float Bs[64][BK + 1];
    int tid = threadIdx.x;
    int bn = blockIdx.x, bm = blockIdx.y;
    int tx = tid & 15, ty = tid >> 4;
    int row0 = bm * 64, col0 = bn * 64;

    float acc[4][4] = {};

    for (int k0 = 0; k0 < K; k0 += BK) {
        int r = tid >> 2;            // 0..63
        int c = (tid & 3) * 4;       // 0,4,8,12
        {
            int gr = row0 + r;
            float4 v = make_float4(0.f, 0.f, 0.f, 0.f);
            if (gr < M) v = *(const float4*)&A[(long long)gr * K + k0 + c];
            As[r][c] = v.x; As[r][c + 1] = v.y; As[r][c + 2] = v.z; As[r][c + 3] = v.w;
        }
        {
            int gc = col0 + r;
            float4 w = make_float4(0.f, 0.f, 0.f, 0.f);
            if (gc < N) w = *(const float4*)&B[(long long)gc * K + k0 + c];
            Bs[r][c] = w.x; Bs[r][c + 1] = w.y; Bs[r][c + 2] = w.z; Bs[r][c + 3] = w.w;
        }
        __syncthreads();
        #pragma unroll
        for (int kk = 0; kk < BK; ++kk) {
            float a[4], b[4];
            #pragma unroll
            for (int i = 0; i < 4; i++) a[i] = As[ty * 4 + i][kk];
            #pragma unroll
            for (int j = 0; j < 4; j++) b[j] = Bs[tx * 4 + j][kk];
            #pragma unroll
            for (int i = 0; i < 4; i++)
                #pragma unroll
                for (int j = 0; j < 4; j++)
                    acc[i][j] += a[i] * b[j];
        }
        __syncthreads();
    }

    #pragma unroll
    for (int i = 0; i < 4; i++) {
        int r = row0 + ty * 4 + i;
        if (r >= M) continue;
        #pragma unroll
        for (int j = 0; j < 4; j++) {
            int c = col0 + tx * 4 + j;
            if (c >= N) continue;
            float v = acc[i][j] + bias[c];
            if (RELU) v = fmaxf(v, 0.0f);
            stf(&C[(long long)r * N + c], v);
        }
    }
}

// ---------------- fused SAGE layer GEMM ----------------
// C[M,HID] = relu( A1@B1^T + bias + A2@B2^T ),  A1 = mean (fp32), A2 = h (TH)
// K = N = HID = 256.

template <typename TH>
__global__ __launch_bounds__(256) void gemm_layer(const float* __restrict__ A1,
                                                  const TH* __restrict__ A2,
                                                  const float* __restrict__ B1,
                                                  const float* __restrict__ B2,
                                                  const float* __restrict__ bias,
                                                  TH* __restrict__ C, int M) {
    const int K = HID, N = HID, BK = 16;
    __shared__ float As1[64][BK + 1];
    __shared__ float As2[64][BK + 1];
    __shared__ float Bs1[64][BK + 1];
    __shared__ float Bs2[64][BK + 1];
    int tid = threadIdx.x;
    int bn = blockIdx.x, bm = blockIdx.y;
    int tx = tid & 15, ty = tid >> 4;
    int row0 = bm * 64, col0 = bn * 64;

    float acc[4][4] = {};

    for (int k0 = 0; k0 < K; k0 += BK) {
        int r = tid >> 2;
        int c = (tid & 3) * 4;
        int gr = row0 + r;
        if (gr < M) {
            const float4 v = *(const float4*)&A1[(long long)gr * K + k0 + c];
            As1[r][c] = v.x; As1[r][c + 1] = v.y; As1[r][c + 2] = v.z; As1[r][c + 3] = v.w;
            const TH* hp = &A2[(long long)gr * K + k0 + c];
            if constexpr (std::is_same<TH, float>::value) {
                const float4 w = *(const float4*)hp;
                As2[r][c] = w.x; As2[r][c + 1] = w.y; As2[r][c + 2] = w.z; As2[r][c + 3] = w.w;
            } else {
                #pragma unroll
                for (int j = 0; j < 4; j++) As2[r][c + j] = ldf(hp + j);
            }
        } else {
            #pragma unroll
            for (int j = 0; j < 4; j++) { As1[r][c + j] = 0.f; As2[r][c + j] = 0.f; }
        }
        {
            int gc = col0 + r;   // always < N here (N=256, grid.x=4)
            const float4 b1 = *(const float4*)&B1[(long long)gc * K + k0 + c];
            Bs1[r][c] = b1.x; Bs1[r][c + 1] = b1.y; Bs1[r][c + 2] = b1.z; Bs1[r][c + 3] = b1.w;
            const float4 b2 = *(const float4*)&B2[(long long)gc * K + k0 + c];
            Bs2[r][c] = b2.x; Bs2[r][c + 1] = b2.y; Bs2[r][c + 2] = b2.z; Bs2[r][c + 3] = b2.w;
        }
        __syncthreads();
        #pragma unroll
        for (int kk = 0; kk < BK; ++kk) {
            float a1[4], a2[4], b1v[4], b2v[4];
            #pragma unroll
            for (int i = 0; i < 4; i++) { a1[i] = As1[ty * 4 + i][kk]; a2[i] = As2[ty * 4 + i][kk]; }
            #pragma unroll
            for (int j = 0; j < 4; j++) { b1v[j] = Bs1[tx * 4 + j][kk]; b2v[j] = Bs2[tx * 4 + j][kk]; }
            #pragma unroll
            for (int i = 0; i < 4; i++)
                #pragma unroll
                for (int j = 0; j < 4; j++)
                    acc[i][j] += a1[i] * b1v[j] + a2[i] * b2v[j];
        }
        __syncthreads();
    }

    #pragma unroll
    for (int i = 0; i < 4; i++) {
        int r = row0 + ty * 4 + i;
        if (r >= M) continue;
        #pragma unroll
        for (int j = 0; j < 4; j++) {
            int c = col0 + tx * 4 + j;
            float v = fmaxf(acc[i][j] + bias[c], 0.0f);
            stf(&C[(long long)r * N + c], v);
        }
    }
}

// ---------------- prediction head, GEMM-ified ----------------
// Step 1: build comb[N_LINKS, 4*HID] = [s, d, s*d, |s-d|]
// Step 2: hidden[N_LINKS, HID] = relu(comb @ wp1^T + bp1)   (gemm_bt)
// Step 3: out[row] = sigmoid(dot(hidden[row], wp2) + bp2)

template <typename TH>
__global__ __launch_bounds__(256) void build_comb(const TH* __restrict__ h,
                                                  const int* __restrict__ src_idx,
                                                  const int* __restrict__ dst_idx,
                                                  float* __restrict__ comb) {
    int row = blockIdx.x;
    int t = threadIdx.x;
    int s = clampi(src_idx[row], N_NODES);
    int d = clampi(dst_idx[row], N_NODES);
    float sv = ldf(&h[(long long)s * HID + t]);
    float dv = ldf(&h[(long long)d * HID + t]);
    float* cr = &comb[(long long)row * (4 * HID)];
    cr[t]           = sv;
    cr[HID + t]     = dv;
    cr[2 * HID + t] = sv * dv;
    cr[3 * HID + t] = fabsf(sv - dv);
}

// one wave (64 lanes) per link row
__global__ __launch_bounds__(256) void pred_final(const float* __restrict__ hidden,
                                                  const float* __restrict__ wp2,
                                                  const float* __restrict__ bp2,
                                                  float* __restrict__ out) {
    int wave = threadIdx.x >> 6;
    int lane = threadIdx.x & 63;
    int row = blockIdx.x * 4 + wave;
    if (row >= N_LINKS) return;
    const float4 hv = *(const float4*)&hidden[(long long)row * HID + lane * 4];
    const float4 wv = *(const float4*)&wp2[lane * 4];
    float v = hv.x * wv.x + hv.y * wv.y + hv.z * wv.z + hv.w * wv.w;
    #pragma unroll
    for (int off = 32; off > 0; off >>= 1) v += __shfl_down(v, off, 64);
    if (lane == 0) out[row] = 1.0f / (1.0f + expf(-(v + bp2[0])));
}

// ---------------- pipeline (templated on h-storage type) ----------------

template <typename TH>
static void run_pipeline(const float* x, const int* e_src, const int* e_dst,
                         const int* src_idx, const int* dst_idx,
                         const float* w_emb, const float* b_emb,
                         const float* wl0, const float* bl0, const float* wr0,
                         const float* wl1, const float* bl1, const float* wr1,
                         const float* wp1, const float* bp1,
                         const float* wp2, const float* bp2,
                         float* out, char* ws, hipStream_t stream) {
    const long long NH = (long long)N_NODES * HID;
    float* agg = (float*)ws;                       // NH fp32 (102.4 MB)
    TH*    h0  = (TH*)(ws + NH * sizeof(float));   // NH TH
    TH*    h1  = h0 + NH;                          // NH TH
    float* deg = (float*)((char*)(h1 + NH));       // N_NODES fp32

    // after the last gemm_layer, agg is dead: reuse it for the pred head
    float* comb   = agg;                                   // 16384*1024 fp32 = 67.1 MB
    float* hidden = agg + (long long)N_LINKS * 4 * HID;    // 16384*256 fp32 = 16.8 MB

    const int seedBlk = (int)((NH + 255) / 256);
    const long long scTot = (long long)N_EDGES * (HID / 4);
    const int scBlk = (int)((scTot + 255) / 256);
    const int mBlk = (int)(((long long)N_NODES * (HID / 4) + 255) / 256);
    dim3 ggrid(HID / 64, (N_NODES + 63) / 64);

    zero_f32<<<(N_NODES + 255) / 256, 256, 0, stream>>>(deg, N_NODES);
    deg_kernel<<<(N_EDGES + 255) / 256, 256, 0, stream>>>(e_dst, deg, N_EDGES);

    gemm_bt<TH, false><<<ggrid, 256, 0, stream>>>(x, w_emb, b_emb, h0, N_NODES, HID, FEAT);

    // layer 0: h1 = relu(mean(h0) @ wl0^T + bl0 + h0 @ wr0^T)
    seed_agg<TH><<<seedBlk, 256, 0, stream>>>(h0, agg, NH);
    scatter_kernel<TH><<<scBlk, 256, 0, stream>>>(h0, e_src, e_dst, agg, N_EDGES);
    mean_kernel<<<mBlk, 256, 0, stream>>>(agg, deg, N_NODES);
    gemm_layer<TH><<<ggrid, 256, 0, stream>>>(agg, h0, wl0, wr0, bl0, h1, N_NODES);

    // layer 1: h0 = relu(mean(h1) @ wl1^T + bl1 + h1 @ wr1^T)
    seed_agg<TH><<<seedBlk, 256, 0, stream>>>(h1, agg, NH);
    scatter_kernel<TH><<<scBlk, 256, 0, stream>>>(h1, e_src, e_dst, agg, N_EDGES);
    mean_kernel<<<mBlk, 256, 0, stream>>>(agg, deg, N_NODES);
    gemm_layer<TH><<<ggrid, 256, 0, stream>>>(agg, h1, wl1, wr1, bl1, h0, N_NODES);

    // prediction head (GEMM-shaped)
    build_comb<TH><<<N_LINKS, 256, 0, stream>>>(h0, src_idx, dst_idx, comb);
    {
        dim3 pgrid(HID / 64, N_LINKS / 64);
        gemm_bt<float, true><<<pgrid, 256, 0, stream>>>(comb, wp1, bp1, hidden,
                                                        N_LINKS, HID, 4 * HID);
    }
    pred_final<<<N_LINKS / 4, 256, 0, stream>>>(hidden, wp2, bp2, out);
}

// ---------------- launch ----------------

extern "C" void kernel_launch(void* const* d_in, const int* in_sizes, int n_in,
                              void* d_out, int out_size, void* d_ws, size_t ws_size,
                              hipStream_t stream) {
    const float* x          = (const float*)d_in[0];
    const int*   edge_index = (const int*)d_in[1];
    const int*   e_src      = edge_index;            // row 0
    const int*   e_dst      = edge_index + N_EDGES;  // row 1
    const int*   src_idx    = (const int*)d_in[3];
    const int*   dst_idx    = (const int*)d_in[4];
    const float* w_emb      = (const float*)d_in[5];
    const float* b_emb      = (const float*)d_in[6];
    const float* wl0        = (const float*)d_in[8];
    const float* bl0        = (const float*)d_in[9];
    const float* wr0        = (const float*)d_in[10];
    const float* wl1        = (const float*)d_in[13];
    const float* bl1        = (const float*)d_in[14];
    const float* wr1        = (const float*)d_in[15];
    const float* wp1        = (const float*)d_in[18];
    const float* bp1        = (const float*)d_in[19];
    const float* wp2        = (const float*)d_in[20];
    const float* bp2        = (const float*)d_in[21];
    float* out = (float*)d_out;

    const size_t NH = (size_t)N_NODES * HID;
    const size_t need_f32  = NH * 4 + 2 * NH * 4 + (size_t)N_NODES * 4;  // agg + 2 fp32 h + deg
    const size_t need_bf16 = NH * 4 + 2 * NH * 2 + (size_t)N_NODES * 4;  // agg + 2 bf16 h + deg

    if (ws_size >= need_f32) {
        run_pipeline<float>(x, e_src, e_dst, src_idx, dst_idx, w_emb, b_emb,
                            wl0, bl0, wr0, wl1, bl1, wr1, wp1, bp1, wp2, bp2,
                            out, (char*)d_ws, stream);
    } else if (ws_size >= need_bf16) {
        run_pipeline<__hip_bfloat16>(x, e_src, e_dst, src_idx, dst_idx, w_emb, b_emb,
                                     wl0, bl0, wr0, wl1, bl1, wr1, wp1, bp1, wp2, bp2,
                                     out, (char*)d_ws, stream);
    } else {
        // workspace too small for any valid plan — emit zeros (visible failure, no fault)
        zero_f32<<<(out_size + 255) / 256, 256, 0, stream>>>(out, out_size);
    }
}

// Round 5
// 2109.052 us; speedup vs baseline: 4.3595x; 2.6260x over previous
//
#include <hip/hip_runtime.h>
#include <hip/hip_bf16.h>
#include <cstdint>
#include <type_traits>

#define N_NODES 100000
#define N_EDGES 500000
#define FEAT 128
#define HID 256
#define N_LINKS 16384

#define SCAN_CH 1024
#define SCAN_NB ((N_NODES + SCAN_CH - 1) / SCAN_CH)   // 98

// ---- generic scalar load/store (fp32 or bf16 storage) ----
__device__ __forceinline__ float ldf(const float* p) { return *p; }
__device__ __forceinline__ float ldf(const __hip_bfloat16* p) { return __bfloat162float(*p); }
__device__ __forceinline__ void stf(float* p, float v) { *p = v; }
__device__ __forceinline__ void stf(__hip_bfloat16* p, float v) { *p = __float2bfloat16(v); }

// 4-wide load/store (16B fp32 / 8B bf16), alignment guaranteed by layout
__device__ __forceinline__ void load4(const float* p, float v[4]) {
    const float4 q = *(const float4*)p;
    v[0] = q.x; v[1] = q.y; v[2] = q.z; v[3] = q.w;
}
__device__ __forceinline__ void load4(const __hip_bfloat16* p, float v[4]) {
    const uint2 q = *(const uint2*)p;
    v[0] = __uint_as_float(q.x << 16);
    v[1] = __uint_as_float(q.x & 0xffff0000u);
    v[2] = __uint_as_float(q.y << 16);
    v[3] = __uint_as_float(q.y & 0xffff0000u);
}
__device__ __forceinline__ void store4(float* p, const float v[4]) {
    *(float4*)p = make_float4(v[0], v[1], v[2], v[3]);
}
__device__ __forceinline__ void store4(__hip_bfloat16* p, const float v[4]) {
    __hip_bfloat16 b[4];
    b[0] = __float2bfloat16(v[0]); b[1] = __float2bfloat16(v[1]);
    b[2] = __float2bfloat16(v[2]); b[3] = __float2bfloat16(v[3]);
    *(uint2*)p = *(const uint2*)b;
}

// defensive: any out-of-range index becomes 0 (wrong answer, not a fault)
__device__ __forceinline__ int clampi(int v, int n) { return ((unsigned)v < (unsigned)n) ? v : 0; }

// ---------------- utility ----------------

__global__ void zero_f32(float* p, int n) {
    int i = blockIdx.x * blockDim.x + threadIdx.x;
    if (i < n) p[i] = 0.0f;
}
__global__ void zero_i32(int* p, int n) {
    int i = blockIdx.x * blockDim.x + threadIdx.x;
    if (i < n) p[i] = 0;
}

// ---------------- CSR build ----------------

__global__ void count_deg(const int* __restrict__ dst, int* __restrict__ deg, int nE) {
    int e = blockIdx.x * blockDim.x + threadIdx.x;
    if (e < nE) atomicAdd(&deg[clampi(dst[e], N_NODES)], 1);
}

// per-chunk sums: block b sums deg[b*1024 .. +1023]
__global__ __launch_bounds__(256) void csr_block_sums(const int* __restrict__ deg, int* __restrict__ bsum) {
    __shared__ int red[256];
    int b = blockIdx.x, t = threadIdx.x;
    int s = 0;
    #pragma unroll
    for (int j = 0; j < 4; j++) {
        int i = b * SCAN_CH + t + j * 256;
        if (i < N_NODES) s += deg[i];
    }
    red[t] = s; __syncthreads();
    for (int o = 128; o > 0; o >>= 1) {
        if (t < o) red[t] += red[t + o];
        __syncthreads();
    }
    if (t == 0) bsum[b] = red[0];
}

// single-block exclusive scan of bsum[SCAN_NB] -> bpre
__global__ __launch_bounds__(128) void csr_scan_partials(const int* __restrict__ bsum, int* __restrict__ bpre) {
    __shared__ int sc[128];
    int t = threadIdx.x;
    int v = (t < SCAN_NB) ? bsum[t] : 0;
    sc[t] = v; __syncthreads();
    for (int o = 1; o < 128; o <<= 1) {
        int x = (t >= o) ? sc[t - o] : 0;
        __syncthreads();
        sc[t] += x;
        __syncthreads();
    }
    if (t < SCAN_NB) bpre[t] = sc[t] - v;   // exclusive
}

// per-chunk: rowptr[i] = bpre[b] + exclusive-prefix within chunk
__global__ __launch_bounds__(256) void csr_write_rowptr(const int* __restrict__ deg,
                                                        const int* __restrict__ bpre,
                                                        int* __restrict__ rowptr) {
    __shared__ int sc[256];
    int b = blockIdx.x, t = threadIdx.x;
    int base = bpre[b];
    int i0 = b * SCAN_CH + t * 4;
    int d[4];
    int s = 0;
    #pragma unroll
    for (int j = 0; j < 4; j++) {
        d[j] = (i0 + j < N_NODES) ? deg[i0 + j] : 0;
        s += d[j];
    }
    sc[t] = s; __syncthreads();
    for (int o = 1; o < 256; o <<= 1) {
        int x = (t >= o) ? sc[t - o] : 0;
        __syncthreads();
        sc[t] += x;
        __syncthreads();
    }
    int pre = base + sc[t] - s;   // exclusive across threads
    #pragma unroll
    for (int j = 0; j < 4; j++) {
        if (i0 + j < N_NODES) rowptr[i0 + j] = pre;
        pre += d[j];
    }
}

// scatter src ids into buckets; rowptr drifts to row_end
__global__ void fill_buckets(const int* __restrict__ src, const int* __restrict__ dst,
                             int* __restrict__ rowptr, int* __restrict__ ebuf, int nE) {
    int e = blockIdx.x * blockDim.x + threadIdx.x;
    if (e >= nE) return;
    int d = clampi(dst[e], N_NODES);
    int pos = atomicAdd(&rowptr[d], 1);
    if (pos < nE) ebuf[pos] = clampi(src[e], N_NODES);
}

// DETERMINISM: fill_buckets slots edges in atomic arrival order, which varies
// run-to-run -> fp32 gather sums change at the 1e-6 level -> bf16 rounding of h
// flips ulps -> post-timing absmax drifts past threshold (seen in R4).
// Sorting each row segment makes the summation order a pure function of the
// input multiset (equal keys are interchangeable), hence bit-exact every call.
__global__ void sort_rows(const int* __restrict__ rowend, const int* __restrict__ deg,
                          int* __restrict__ ebuf) {
    int n = blockIdx.x * blockDim.x + threadIdx.x;
    if (n >= N_NODES) return;
    int end = rowend[n];
    int start = end - deg[n];
    for (int i = start + 1; i < end; i++) {          // insertion sort (mean deg ~5)
        int key = ebuf[i];
        int j = i - 1;
        while (j >= start && ebuf[j] > key) { ebuf[j + 1] = ebuf[j]; j--; }
        ebuf[j + 1] = key;
    }
}

// ---------------- gather aggregation ----------------
// one wave per node: agg[n,:] = (sum_{s in in(n)} h[s,:] + h[n,:]) / (deg+1)

template <typename TH, typename TA>
__global__ __launch_bounds__(256) void gather_agg(const TH* __restrict__ h,
                                                  const int* __restrict__ rowend,
                                                  const int* __restrict__ deg,
                                                  const int* __restrict__ ebuf,
                                                  TA* __restrict__ agg) {
    int wave = threadIdx.x >> 6, lane = threadIdx.x & 63;
    int n = blockIdx.x * 4 + wave;
    if (n >= N_NODES) return;
    int dg  = deg[n];
    int end = rowend[n];
    int start = end - dg;
    float acc[4];
    load4(&h[(long long)n * HID + lane * 4], acc);   // self loop
    for (int e = start; e < end; e++) {
        int s = ebuf[e];
        float v[4];
        load4(&h[(long long)s * HID + lane * 4], v);
        acc[0] += v[0]; acc[1] += v[1]; acc[2] += v[2]; acc[3] += v[3];
    }
    float inv = 1.0f / (float)(dg + 1);
    acc[0] *= inv; acc[1] *= inv; acc[2] *= inv; acc[3] *= inv;
    store4(&agg[(long long)n * HID + lane * 4], acc);
}

// ---------------- generic tiled GEMM: C[M,N] = (relu)(A[M,K] @ B[N,K]^T + bias) ----

template <typename TC, bool RELU>
__global__ __launch_bounds__(256) void gemm_bt(const float* __restrict__ A,
                                               const float* __restrict__ B,
                                               const float* __restrict__ bias,
                                               TC* __restrict__ C,
                                               int M, int N, int K) {
    const int BK = 16;
    __shared__ float As[64][BK + 1];
    __shared__ float Bs[64][BK + 1];
    int tid = threadIdx.x;
    int bn = blockIdx.x, bm = blockIdx.y;
    int tx = tid & 15, ty = tid >> 4;
    int row0 = bm * 64, col0 = bn * 64;

    float acc[4][4] = {};

    for (int k0 = 0; k0 < K; k0 += BK) {
        int r = tid >> 2;
        int c = (tid & 3) * 4;
        {
            int gr = row0 + r;
            float4 v = make_float4(0.f, 0.f, 0.f, 0.f);
            if (gr < M) v = *(const float4*)&A[(long long)gr * K + k0 + c];
            As[r][c] = v.x; As[r][c + 1] = v.y; As[r][c + 2] = v.z; As[r][c + 3] = v.w;
        }
        {
            int gc = col0 + r;
            float4 w = make_float4(0.f, 0.f, 0.f, 0.f);
            if (gc < N) w = *(const float4*)&B[(long long)gc * K + k0 + c];
            Bs[r][c] = w.x; Bs[r][c + 1] = w.y; Bs[r][c + 2] = w.z; Bs[r][c + 3] = w.w;
        }
        __syncthreads();
        #pragma unroll
        for (int kk = 0; kk < BK; ++kk) {
            float a[4], b[4];
            #pragma unroll
            for (int i = 0; i < 4; i++) a[i] = As[ty * 4 + i][kk];
            #pragma unroll
            for (int j = 0; j < 4; j++) b[j] = Bs[tx * 4 + j][kk];
            #pragma unroll
            for (int i = 0; i < 4; i++)
                #pragma unroll
                for (int j = 0; j < 4; j++)
                    acc[i][j] += a[i] * b[j];
        }
        __syncthreads();
    }

    #pragma unroll
    for (int i = 0; i < 4; i++) {
        int r = row0 + ty * 4 + i;
        if (r >= M) continue;
        #pragma unroll
        for (int j = 0; j < 4; j++) {
            int c = col0 + tx * 4 + j;
            if (c >= N) continue;
            float v = acc[i][j] + bias[c];
            if (RELU) v = fmaxf(v, 0.0f);
            stf(&C[(long long)r * N + c], v);
        }
    }
}

// ---------------- fused SAGE layer GEMM ----------------
// C[M,HID] = relu( A1@B1^T + bias + A2@B2^T ),  A1 = mean (TA), A2 = h (TH)

template <typename TH, typename TA>
__global__ __launch_bounds__(256) void gemm_layer(const TA* __restrict__ A1,
                                                  const TH* __restrict__ A2,
                                                  const float* __restrict__ B1,
                                                  const float* __restrict__ B2,
                                                  const float* __restrict__ bias,
                                                  TH* __restrict__ C, int M) {
    const int K = HID, N = HID, BK = 16;
    __shared__ float As1[64][BK + 1];
    __shared__ float As2[64][BK + 1];
    __shared__ float Bs1[64][BK + 1];
    __shared__ float Bs2[64][BK + 1];
    int tid = threadIdx.x;
    int bn = blockIdx.x, bm = blockIdx.y;
    int tx = tid & 15, ty = tid >> 4;
    int row0 = bm * 64, col0 = bn * 64;

    float acc[4][4] = {};

    for (int k0 = 0; k0 < K; k0 += BK) {
        int r = tid >> 2;
        int c = (tid & 3) * 4;
        int gr = row0 + r;
        if (gr < M) {
            float v[4];
            load4(&A1[(long long)gr * K + k0 + c], v);
            As1[r][c] = v[0]; As1[r][c + 1] = v[1]; As1[r][c + 2] = v[2]; As1[r][c + 3] = v[3];
            load4(&A2[(long long)gr * K + k0 + c], v);
            As2[r][c] = v[0]; As2[r][c + 1] = v[1]; As2[r][c + 2] = v[2]; As2[r][c + 3] = v[3];
        } else {
            #pragma unroll
            for (int j = 0; j < 4; j++) { As1[r][c + j] = 0.f; As2[r][c + j] = 0.f; }
        }
        {
            int gc = col0 + r;   // always < N (N=256, grid.x=4)
            const float4 b1 = *(const float4*)&B1[(long long)gc * K + k0 + c];
            Bs1[r][c] = b1.x; Bs1[r][c + 1] = b1.y; Bs1[r][c + 2] = b1.z; Bs1[r][c + 3] = b1.w;
            const float4 b2 = *(const float4*)&B2[(long long)gc * K + k0 + c];
            Bs2[r][c] = b2.x; Bs2[r][c + 1] = b2.y; Bs2[r][c + 2] = b2.z; Bs2[r][c + 3] = b2.w;
        }
        __syncthreads();
        #pragma unroll
        for (int kk = 0; kk < BK; ++kk) {
            float a1[4], a2[4], b1v[4], b2v[4];
            #pragma unroll
            for (int i = 0; i < 4; i++) { a1[i] = As1[ty * 4 + i][kk]; a2[i] = As2[ty * 4 + i][kk]; }
            #pragma unroll
            for (int j = 0; j < 4; j++) { b1v[j] = Bs1[tx * 4 + j][kk]; b2v[j] = Bs2[tx * 4 + j][kk]; }
            #pragma unroll
            for (int i = 0; i < 4; i++)
                #pragma unroll
                for (int j = 0; j < 4; j++)
                    acc[i][j] += a1[i] * b1v[j] + a2[i] * b2v[j];
        }
        __syncthreads();
    }

    #pragma unroll
    for (int i = 0; i < 4; i++) {
        int r = row0 + ty * 4 + i;
        if (r >= M) continue;
        #pragma unroll
        for (int j = 0; j < 4; j++) {
            int c = col0 + tx * 4 + j;
            float v = fmaxf(acc[i][j] + bias[c], 0.0f);
            stf(&C[(long long)r * N + c], v);
        }
    }
}

// ---------------- prediction head ----------------

template <typename TH>
__global__ __launch_bounds__(256) void build_comb(const TH* __restrict__ h,
                                                  const int* __restrict__ src_idx,
                                                  const int* __restrict__ dst_idx,
                                                  float* __restrict__ comb) {
    int row = blockIdx.x;
    int t = threadIdx.x;
    int s = clampi(src_idx[row], N_NODES);
    int d = clampi(dst_idx[row], N_NODES);
    float sv = ldf(&h[(long long)s * HID + t]);
    float dv = ldf(&h[(long long)d * HID + t]);
    float* cr = &comb[(long long)row * (4 * HID)];
    cr[t]           = sv;
    cr[HID + t]     = dv;
    cr[2 * HID + t] = sv * dv;
    cr[3 * HID + t] = fabsf(sv - dv);
}

__global__ __launch_bounds__(256) void pred_final(const float* __restrict__ hidden,
                                                  const float* __restrict__ wp2,
                                                  const float* __restrict__ bp2,
                                                  float* __restrict__ out) {
    int wave = threadIdx.x >> 6;
    int lane = threadIdx.x & 63;
    int row = blockIdx.x * 4 + wave;
    if (row >= N_LINKS) return;
    const float4 hv = *(const float4*)&hidden[(long long)row * HID + lane * 4];
    const float4 wv = *(const float4*)&wp2[lane * 4];
    float v = hv.x * wv.x + hv.y * wv.y + hv.z * wv.z + hv.w * wv.w;
    #pragma unroll
    for (int off = 32; off > 0; off >>= 1) v += __shfl_down(v, off, 64);
    if (lane == 0) out[row] = 1.0f / (1.0f + expf(-(v + bp2[0])));
}

// ---------------- pipeline ----------------

template <typename TH, typename TA>
static void run_pipeline(const float* x, const int* e_src, const int* e_dst,
                         const int* src_idx, const int* dst_idx,
                         const float* w_emb, const float* b_emb,
                         const float* wl0, const float* bl0, const float* wr0,
                         const float* wl1, const float* bl1, const float* wr1,
                         const float* wp1, const float* bp1,
                         const float* wp2, const float* bp2,
                         float* out, char* ws, hipStream_t stream) {
    const long long NH = (long long)N_NODES * HID;
    char* p = ws;
    TH* h0     = (TH*)p;  p += NH * sizeof(TH);
    TA* agg    = (TA*)p;  p += NH * sizeof(TA);
    TH* h1     = (TH*)p;  p += NH * sizeof(TH);
    int* deg   = (int*)p; p += (size_t)N_NODES * 4;
    int* rowptr= (int*)p; p += (size_t)N_NODES * 4;
    int* ebuf  = (int*)p; p += (size_t)N_EDGES * 4;
    int* bsum  = (int*)p; p += 128 * 4;
    int* bpre  = (int*)p; p += 128 * 4;

    // pred-head reuse: agg..h1 region (contiguous, >= 84 MB in both plans)
    float* comb   = (float*)agg;
    float* hidden = comb + (long long)N_LINKS * 4 * HID;

    dim3 ggrid(HID / 64, (N_NODES + 63) / 64);
    const int aggBlk = (N_NODES + 3) / 4;

    // ---- CSR build ----
    zero_i32<<<(N_NODES + 255) / 256, 256, 0, stream>>>(deg, N_NODES);
    count_deg<<<(N_EDGES + 255) / 256, 256, 0, stream>>>(e_dst, deg, N_EDGES);
    csr_block_sums<<<SCAN_NB, 256, 0, stream>>>(deg, bsum);
    csr_scan_partials<<<1, 128, 0, stream>>>(bsum, bpre);
    csr_write_rowptr<<<SCAN_NB, 256, 0, stream>>>(deg, bpre, rowptr);
    fill_buckets<<<(N_EDGES + 255) / 256, 256, 0, stream>>>(e_src, e_dst, rowptr, ebuf, N_EDGES);
    // rowptr now holds row_end per node
    sort_rows<<<(N_NODES + 255) / 256, 256, 0, stream>>>(rowptr, deg, ebuf);

    // ---- embedding ----
    gemm_bt<TH, false><<<ggrid, 256, 0, stream>>>(x, w_emb, b_emb, h0, N_NODES, HID, FEAT);

    // ---- layer 0 ----
    gather_agg<TH, TA><<<aggBlk, 256, 0, stream>>>(h0, rowptr, deg, ebuf, agg);
    gemm_layer<TH, TA><<<ggrid, 256, 0, stream>>>(agg, h0, wl0, wr0, bl0, h1, N_NODES);

    // ---- layer 1 ----
    gather_agg<TH, TA><<<aggBlk, 256, 0, stream>>>(h1, rowptr, deg, ebuf, agg);
    gemm_layer<TH, TA><<<ggrid, 256, 0, stream>>>(agg, h1, wl1, wr1, bl1, h0, N_NODES);

    // ---- prediction head ----
    build_comb<TH><<<N_LINKS, 256, 0, stream>>>(h0, src_idx, dst_idx, comb);
    {
        dim3 pgrid(HID / 64, N_LINKS / 64);
        gemm_bt<float, true><<<pgrid, 256, 0, stream>>>(comb, wp1, bp1, hidden,
                                                        N_LINKS, HID, 4 * HID);
    }
    pred_final<<<N_LINKS / 4, 256, 0, stream>>>(hidden, wp2, bp2, out);
}

// ---------------- launch ----------------

extern "C" void kernel_launch(void* const* d_in, const int* in_sizes, int n_in,
                              void* d_out, int out_size, void* d_ws, size_t ws_size,
                              hipStream_t stream) {
    const float* x          = (const float*)d_in[0];
    const int*   edge_index = (const int*)d_in[1];
    const int*   e_src      = edge_index;            // row 0
    const int*   e_dst      = edge_index + N_EDGES;  // row 1
    const int*   src_idx    = (const int*)d_in[3];
    const int*   dst_idx    = (const int*)d_in[4];
    const float* w_emb      = (const float*)d_in[5];
    const float* b_emb      = (const float*)d_in[6];
    const float* wl0        = (const float*)d_in[8];
    const float* bl0        = (const float*)d_in[9];
    const float* wr0        = (const float*)d_in[10];
    const float* wl1        = (const float*)d_in[13];
    const float* bl1        = (const float*)d_in[14];
    const float* wr1        = (const float*)d_in[15];
    const float* wp1        = (const float*)d_in[18];
    const float* bp1        = (const float*)d_in[19];
    const float* wp2        = (const float*)d_in[20];
    const float* bp2        = (const float*)d_in[21];
    float* out = (float*)d_out;

    const size_t NH = (size_t)N_NODES * HID;
    const size_t ints = (size_t)N_NODES * 8 + (size_t)N_EDGES * 4 + 1024;
    const size_t need_B = NH * (2 + 4 + 2) + ints;   // bf16 h, fp32 agg  (~207.6 MB)
    const size_t need_C = NH * (2 + 2 + 2) + ints;   // bf16 h, bf16 agg (~156.4 MB)

    if (ws_size >= need_B) {
        run_pipeline<__hip_bfloat16, float>(x, e_src, e_dst, src_idx, dst_idx, w_emb, b_emb,
                                            wl0, bl0, wr0, wl1, bl1, wr1, wp1, bp1, wp2, bp2,
                                            out, (char*)d_ws, stream);
    } else if (ws_size >= need_C) {
        run_pipeline<__hip_bfloat16, __hip_bfloat16>(x, e_src, e_dst, src_idx, dst_idx, w_emb, b_emb,
                                                     wl0, bl0, wr0, wl1, bl1, wr1, wp1, bp1, wp2, bp2,
                                                     out, (char*)d_ws, stream);
    } else {
        // workspace too small for any valid plan — emit zeros (visible failure, no fault)
        zero_f32<<<(out_size + 255) / 256, 256, 0, stream>>>(out, out_size);
    }
}

// Round 6
// 766.932 us; speedup vs baseline: 11.9885x; 2.7500x over previous
//
#include <hip/hip_runtime.h>
#include <hip/hip_bf16.h>
#include <cstdint>
#include <type_traits>

#define N_NODES 100000
#define N_EDGES 500000
#define FEAT 128
#define HID 256
#define N_LINKS 16384

#define SCAN_CH 1024
#define SCAN_NB ((N_NODES + SCAN_CH - 1) / SCAN_CH)   // 98

typedef __attribute__((ext_vector_type(8))) short short8;    // 8 bf16 = 4 VGPRs
typedef __attribute__((ext_vector_type(4))) float floatx4;

// ---- scalar load/store ----
__device__ __forceinline__ float ldf(const float* p) { return *p; }
__device__ __forceinline__ float ldf(const __hip_bfloat16* p) { return __bfloat162float(*p); }
__device__ __forceinline__ void stf(float* p, float v) { *p = v; }
__device__ __forceinline__ void stf(__hip_bfloat16* p, float v) { *p = __float2bfloat16(v); }

// 4-wide bf16 load/store (8B)
__device__ __forceinline__ void load4(const __hip_bfloat16* p, float v[4]) {
    const uint2 q = *(const uint2*)p;
    v[0] = __uint_as_float(q.x << 16);
    v[1] = __uint_as_float(q.x & 0xffff0000u);
    v[2] = __uint_as_float(q.y << 16);
    v[3] = __uint_as_float(q.y & 0xffff0000u);
}
__device__ __forceinline__ void store4(__hip_bfloat16* p, const float v[4]) {
    __hip_bfloat16 b[4];
    b[0] = __float2bfloat16(v[0]); b[1] = __float2bfloat16(v[1]);
    b[2] = __float2bfloat16(v[2]); b[3] = __float2bfloat16(v[3]);
    *(uint2*)p = *(const uint2*)b;
}

// defensive: any out-of-range index becomes 0 (wrong answer, not a fault)
__device__ __forceinline__ int clampi(int v, int n) { return ((unsigned)v < (unsigned)n) ? v : 0; }

// ---------------- utility ----------------

__global__ void zero_f32(float* p, int n) {
    int i = blockIdx.x * blockDim.x + threadIdx.x;
    if (i < n) p[i] = 0.0f;
}
__global__ void zero_i32(int* p, int n) {
    int i = blockIdx.x * blockDim.x + threadIdx.x;
    if (i < n) p[i] = 0;
}

// x (float4-wide) -> bf16
__global__ void cvt_x(const float4* __restrict__ x, __hip_bfloat16* __restrict__ xb, int n4) {
    int i = blockIdx.x * blockDim.x + threadIdx.x;
    if (i >= n4) return;
    float4 v = x[i];
    float a[4] = {v.x, v.y, v.z, v.w};
    store4(&xb[(size_t)i * 4], a);
}

// weights -> contiguous bf16 buffer (offsets fixed)
#define WOF_EMB 0
#define WOF_L0  32768
#define WOF_R0  98304
#define WOF_L1  163840
#define WOF_R1  229376
#define WOF_P1  294912
#define W_TOTAL 557056
__global__ void cvt_w(const float* __restrict__ w_emb, const float* __restrict__ wl0,
                      const float* __restrict__ wr0, const float* __restrict__ wl1,
                      const float* __restrict__ wr1, const float* __restrict__ wp1,
                      __hip_bfloat16* __restrict__ wb) {
    int i = blockIdx.x * blockDim.x + threadIdx.x;
    if (i >= W_TOTAL) return;
    float v;
    if      (i < WOF_L0) v = w_emb[i - WOF_EMB];
    else if (i < WOF_R0) v = wl0[i - WOF_L0];
    else if (i < WOF_L1) v = wr0[i - WOF_R0];
    else if (i < WOF_R1) v = wl1[i - WOF_L1];
    else if (i < WOF_P1) v = wr1[i - WOF_R1];
    else                 v = wp1[i - WOF_P1];
    wb[i] = __float2bfloat16(v);
}

// ---------------- CSR build ----------------

__global__ void count_deg(const int* __restrict__ dst, int* __restrict__ deg, int nE) {
    int e = blockIdx.x * blockDim.x + threadIdx.x;
    if (e < nE) atomicAdd(&deg[clampi(dst[e], N_NODES)], 1);
}

__global__ __launch_bounds__(256) void csr_block_sums(const int* __restrict__ deg, int* __restrict__ bsum) {
    __shared__ int red[256];
    int b = blockIdx.x, t = threadIdx.x;
    int s = 0;
    #pragma unroll
    for (int j = 0; j < 4; j++) {
        int i = b * SCAN_CH + t + j * 256;
        if (i < N_NODES) s += deg[i];
    }
    red[t] = s; __syncthreads();
    for (int o = 128; o > 0; o >>= 1) {
        if (t < o) red[t] += red[t + o];
        __syncthreads();
    }
    if (t == 0) bsum[b] = red[0];
}

__global__ __launch_bounds__(128) void csr_scan_partials(const int* __restrict__ bsum, int* __restrict__ bpre) {
    __shared__ int sc[128];
    int t = threadIdx.x;
    int v = (t < SCAN_NB) ? bsum[t] : 0;
    sc[t] = v; __syncthreads();
    for (int o = 1; o < 128; o <<= 1) {
        int x = (t >= o) ? sc[t - o] : 0;
        __syncthreads();
        sc[t] += x;
        __syncthreads();
    }
    if (t < SCAN_NB) bpre[t] = sc[t] - v;   // exclusive
}

__global__ __launch_bounds__(256) void csr_write_rowptr(const int* __restrict__ deg,
                                                        const int* __restrict__ bpre,
                                                        int* __restrict__ rowptr) {
    __shared__ int sc[256];
    int b = blockIdx.x, t = threadIdx.x;
    int base = bpre[b];
    int i0 = b * SCAN_CH + t * 4;
    int d[4];
    int s = 0;
    #pragma unroll
    for (int j = 0; j < 4; j++) {
        d[j] = (i0 + j < N_NODES) ? deg[i0 + j] : 0;
        s += d[j];
    }
    sc[t] = s; __syncthreads();
    for (int o = 1; o < 256; o <<= 1) {
        int x = (t >= o) ? sc[t - o] : 0;
        __syncthreads();
        sc[t] += x;
        __syncthreads();
    }
    int pre = base + sc[t] - s;
    #pragma unroll
    for (int j = 0; j < 4; j++) {
        if (i0 + j < N_NODES) rowptr[i0 + j] = pre;
        pre += d[j];
    }
}

__global__ void fill_buckets(const int* __restrict__ src, const int* __restrict__ dst,
                             int* __restrict__ rowptr, int* __restrict__ ebuf, int nE) {
    int e = blockIdx.x * blockDim.x + threadIdx.x;
    if (e >= nE) return;
    int d = clampi(dst[e], N_NODES);
    int pos = atomicAdd(&rowptr[d], 1);
    if (pos < nE) ebuf[pos] = clampi(src[e], N_NODES);
}

// DETERMINISM: fill_buckets slots edges in atomic arrival order (varies per run).
// Sorting each row makes summation order a pure function of the input multiset
// -> bit-exact output every call (required by the post-timing re-check; see R4).
__global__ void sort_rows(const int* __restrict__ rowend, const int* __restrict__ deg,
                          int* __restrict__ ebuf) {
    int n = blockIdx.x * blockDim.x + threadIdx.x;
    if (n >= N_NODES) return;
    int end = rowend[n];
    int start = end - deg[n];
    for (int i = start + 1; i < end; i++) {          // insertion sort (mean deg ~5)
        int key = ebuf[i];
        int j = i - 1;
        while (j >= start && ebuf[j] > key) { ebuf[j + 1] = ebuf[j]; j--; }
        ebuf[j + 1] = key;
    }
}

// ---------------- gather aggregation ----------------
// one wave per node: agg[n,:] = (sum_{s in in(n)} h[s,:] + h[n,:]) / (deg+1)

__global__ __launch_bounds__(256) void gather_agg(const __hip_bfloat16* __restrict__ h,
                                                  const int* __restrict__ rowend,
                                                  const int* __restrict__ deg,
                                                  const int* __restrict__ ebuf,
                                                  __hip_bfloat16* __restrict__ agg) {
    int wave = threadIdx.x >> 6, lane = threadIdx.x & 63;
    int n = blockIdx.x * 4 + wave;
    if (n >= N_NODES) return;
    int dg  = deg[n];
    int end = rowend[n];
    int start = end - dg;
    float acc[4];
    load4(&h[(long long)n * HID + lane * 4], acc);   // self loop
    for (int e = start; e < end; e++) {
        int s = ebuf[e];
        float v[4];
        load4(&h[(long long)s * HID + lane * 4], v);
        acc[0] += v[0]; acc[1] += v[1]; acc[2] += v[2]; acc[3] += v[3];
    }
    float inv = 1.0f / (float)(dg + 1);
    acc[0] *= inv; acc[1] *= inv; acc[2] *= inv; acc[3] *= inv;
    store4(&agg[(long long)n * HID + lane * 4], acc);
}

// ---------------- MFMA GEMM ----------------
// C[M,256] = (relu)( A1[M,K]@B1[256,K]^T (+ A2@B2^T) + bias )
// bf16 inputs, fp32 accumulate via v_mfma_f32_16x16x32_bf16, no LDS.
// Wave tile: 32 rows x 128 cols = 2x8 tiles of 16x16. Block: 4 waves = 64 rows x 256 cols.
// Fragment layouts (guide-verified m89/m91/m120):
//   A-frag: A[m = lane&15][k = (lane>>4)*8 + j]   (16B contiguous per lane)
//   B-frag: W[n = lane&15][k = (lane>>4)*8 + j]   (W row-major [N][K], i.e. B^T input)
//   C/D   : col = lane&15, row = (lane>>4)*4 + reg

template <bool DUAL, typename TC, bool RELU>
__global__ __launch_bounds__(256) void mfma_gemm(const __hip_bfloat16* __restrict__ A1,
                                                 const __hip_bfloat16* __restrict__ A2,
                                                 const __hip_bfloat16* __restrict__ B1,
                                                 const __hip_bfloat16* __restrict__ B2,
                                                 const float* __restrict__ bias,
                                                 TC* __restrict__ C, int M, int K) {
    const int N = 256;
    int w = threadIdx.x >> 6, lane = threadIdx.x & 63;
    int quad = lane >> 4, l16 = lane & 15;
    int row0 = blockIdx.x * 64 + (w >> 1) * 32;
    int colbase = (w & 1) * 128;

    floatx4 acc[2][8] = {};

    int r0 = row0 + l16;       if (r0 >= M) r0 = M - 1;   // clamped; stores guarded
    int r1 = row0 + 16 + l16;  if (r1 >= M) r1 = M - 1;

    const short* A1s = (const short*)A1;
    const short* A2s = (const short*)A2;
    const short* B1s = (const short*)B1;
    const short* B2s = (const short*)B2;

    for (int k0 = 0; k0 < K; k0 += 32) {
        int ka = k0 + quad * 8;
        short8 a1_0 = *(const short8*)(A1s + (size_t)r0 * K + ka);
        short8 a1_1 = *(const short8*)(A1s + (size_t)r1 * K + ka);
        short8 a2_0, a2_1;
        if (DUAL) {
            a2_0 = *(const short8*)(A2s + (size_t)r0 * K + ka);
            a2_1 = *(const short8*)(A2s + (size_t)r1 * K + ka);
        }
        #pragma unroll
        for (int ct = 0; ct < 8; ct++) {
            int col = colbase + ct * 16 + l16;
            short8 b1 = *(const short8*)(B1s + (size_t)col * K + ka);
            acc[0][ct] = __builtin_amdgcn_mfma_f32_16x16x32_bf16(a1_0, b1, acc[0][ct], 0, 0, 0);
            acc[1][ct] = __builtin_amdgcn_mfma_f32_16x16x32_bf16(a1_1, b1, acc[1][ct], 0, 0, 0);
            if (DUAL) {
                short8 b2 = *(const short8*)(B2s + (size_t)col * K + ka);
                acc[0][ct] = __builtin_amdgcn_mfma_f32_16x16x32_bf16(a2_0, b2, acc[0][ct], 0, 0, 0);
                acc[1][ct] = __builtin_amdgcn_mfma_f32_16x16x32_bf16(a2_1, b2, acc[1][ct], 0, 0, 0);
            }
        }
    }

    #pragma unroll
    for (int rt = 0; rt < 2; rt++) {
        #pragma unroll
        for (int ct = 0; ct < 8; ct++) {
            int c = colbase + ct * 16 + l16;
            float bc = bias[c];
            #pragma unroll
            for (int i = 0; i < 4; i++) {
                int r = row0 + rt * 16 + quad * 4 + i;
                if (r < M) {
                    float v = acc[rt][ct][i] + bc;
                    if (RELU) v = fmaxf(v, 0.0f);
                    stf(&C[(size_t)r * N + c], v);
                }
            }
        }
    }
}

// ---------------- prediction head ----------------

__global__ __launch_bounds__(256) void build_comb(const __hip_bfloat16* __restrict__ h,
                                                  const int* __restrict__ src_idx,
                                                  const int* __restrict__ dst_idx,
                                                  __hip_bfloat16* __restrict__ comb) {
    int row = blockIdx.x;
    int t = threadIdx.x;
    int s = clampi(src_idx[row], N_NODES);
    int d = clampi(dst_idx[row], N_NODES);
    float sv = ldf(&h[(long long)s * HID + t]);
    float dv = ldf(&h[(long long)d * HID + t]);
    __hip_bfloat16* cr = &comb[(long long)row * (4 * HID)];
    stf(&cr[t], sv);
    stf(&cr[HID + t], dv);
    stf(&cr[2 * HID + t], sv * dv);
    stf(&cr[3 * HID + t], fabsf(sv - dv));
}

__global__ __launch_bounds__(256) void pred_final(const float* __restrict__ hidden,
                                                  const float* __restrict__ wp2,
                                                  const float* __restrict__ bp2,
                                                  float* __restrict__ out) {
    int wave = threadIdx.x >> 6;
    int lane = threadIdx.x & 63;
    int row = blockIdx.x * 4 + wave;
    if (row >= N_LINKS) return;
    const float4 hv = *(const float4*)&hidden[(long long)row * HID + lane * 4];
    const float4 wv = *(const float4*)&wp2[lane * 4];
    float v = hv.x * wv.x + hv.y * wv.y + hv.z * wv.z + hv.w * wv.w;
    #pragma unroll
    for (int off = 32; off > 0; off >>= 1) v += __shfl_down(v, off, 64);
    if (lane == 0) out[row] = 1.0f / (1.0f + expf(-(v + bp2[0])));
}

// ---------------- launch ----------------

extern "C" void kernel_launch(void* const* d_in, const int* in_sizes, int n_in,
                              void* d_out, int out_size, void* d_ws, size_t ws_size,
                              hipStream_t stream) {
    const float* x          = (const float*)d_in[0];
    const int*   edge_index = (const int*)d_in[1];
    const int*   e_src      = edge_index;            // row 0
    const int*   e_dst      = edge_index + N_EDGES;  // row 1
    const int*   src_idx    = (const int*)d_in[3];
    const int*   dst_idx    = (const int*)d_in[4];
    const float* w_emb      = (const float*)d_in[5];
    const float* b_emb      = (const float*)d_in[6];
    const float* wl0        = (const float*)d_in[8];
    const float* bl0        = (const float*)d_in[9];
    const float* wr0        = (const float*)d_in[10];
    const float* wl1        = (const float*)d_in[13];
    const float* bl1        = (const float*)d_in[14];
    const float* wr1        = (const float*)d_in[15];
    const float* wp1        = (const float*)d_in[18];
    const float* bp1        = (const float*)d_in[19];
    const float* wp2        = (const float*)d_in[20];
    const float* bp2        = (const float*)d_in[21];
    float* out = (float*)d_out;

    typedef __hip_bfloat16 bf16;
    const size_t NH = (size_t)N_NODES * HID;

    // workspace plan (~183 MB; ws proven >= 205 MB by R2)
    char* p = (char*)d_ws;
    bf16* h0   = (bf16*)p;  p += NH * 2;                       // 51.2 MB
    bf16* h1   = (bf16*)p;  p += NH * 2;                       // 51.2 MB
    bf16* agg  = (bf16*)p;  p += NH * 2;                       // 51.2 MB
    bf16* xb   = (bf16*)p;  p += (size_t)N_NODES * FEAT * 2;   // 25.6 MB
    bf16* wb   = (bf16*)p;  p += (size_t)W_TOTAL * 2;          // 1.1 MB
    p = (char*)(((uintptr_t)p + 255) & ~(uintptr_t)255);
    int* deg    = (int*)p; p += (size_t)N_NODES * 4;
    int* rowptr = (int*)p; p += (size_t)N_NODES * 4;
    int* ebuf   = (int*)p; p += (size_t)N_EDGES * 4;
    int* bsum   = (int*)p; p += 128 * 4;
    int* bpre   = (int*)p; p += 128 * 4;
    const size_t need = (size_t)(p - (char*)d_ws);

    if (ws_size < need) {   // visible failure, no fault
        zero_f32<<<(out_size + 255) / 256, 256, 0, stream>>>(out, out_size);
        return;
    }

    // aliases (regions dead by the time they're reused):
    bf16*  comb   = agg;         // [16384][1024] bf16 = 33.6 MB <= 51.2
    float* hidden = (float*)h1;  // [16384][256] fp32 = 16.8 MB <= 51.2

    // ---- CSR build ----
    zero_i32<<<(N_NODES + 255) / 256, 256, 0, stream>>>(deg, N_NODES);
    count_deg<<<(N_EDGES + 255) / 256, 256, 0, stream>>>(e_dst, deg, N_EDGES);
    csr_block_sums<<<SCAN_NB, 256, 0, stream>>>(deg, bsum);
    csr_scan_partials<<<1, 128, 0, stream>>>(bsum, bpre);
    csr_write_rowptr<<<SCAN_NB, 256, 0, stream>>>(deg, bpre, rowptr);
    fill_buckets<<<(N_EDGES + 255) / 256, 256, 0, stream>>>(e_src, e_dst, rowptr, ebuf, N_EDGES);
    sort_rows<<<(N_NODES + 255) / 256, 256, 0, stream>>>(rowptr, deg, ebuf);
    // rowptr now holds row_end per node

    // ---- bf16 conversions ----
    cvt_x<<<((N_NODES * FEAT / 4) + 255) / 256, 256, 0, stream>>>((const float4*)x, xb, N_NODES * FEAT / 4);
    cvt_w<<<(W_TOTAL + 255) / 256, 256, 0, stream>>>(w_emb, wl0, wr0, wl1, wr1, wp1, wb);

    const int ggrid = (N_NODES + 63) / 64;   // 1563

    // ---- embedding: h0 = xb @ w_emb^T + b_emb ----
    mfma_gemm<false, bf16, false><<<ggrid, 256, 0, stream>>>(
        xb, nullptr, wb + WOF_EMB, nullptr, b_emb, h0, N_NODES, FEAT);

    // ---- layer 0: h1 = relu(agg@wl0^T + bl0 + h0@wr0^T) ----
    gather_agg<<<(N_NODES + 3) / 4, 256, 0, stream>>>(h0, rowptr, deg, ebuf, agg);
    mfma_gemm<true, bf16, true><<<ggrid, 256, 0, stream>>>(
        agg, h0, wb + WOF_L0, wb + WOF_R0, bl0, h1, N_NODES, HID);

    // ---- layer 1: h0 = relu(agg@wl1^T + bl1 + h1@wr1^T) ----
    gather_agg<<<(N_NODES + 3) / 4, 256, 0, stream>>>(h1, rowptr, deg, ebuf, agg);
    mfma_gemm<true, bf16, true><<<ggrid, 256, 0, stream>>>(
        agg, h1, wb + WOF_L1, wb + WOF_R1, bl1, h0, N_NODES, HID);

    // ---- prediction head ----
    build_comb<<<N_LINKS, 256, 0, stream>>>(h0, src_idx, dst_idx, comb);
    mfma_gemm<false, float, true><<<(N_LINKS + 63) / 64, 256, 0, stream>>>(
        comb, nullptr, wb + WOF_P1, nullptr, bp1, hidden, N_LINKS, 4 * HID);
    pred_final<<<N_LINKS / 4, 256, 0, stream>>>(hidden, wp2, bp2, out);
}

// Round 7
// 666.955 us; speedup vs baseline: 13.7856x; 1.1499x over previous
//
#include <hip/hip_runtime.h>
#include <hip/hip_bf16.h>
#include <cstdint>
#include <type_traits>

#define N_NODES 100000
#define N_EDGES 500000
#define FEAT 128
#define HID 256
#define N_LINKS 16384

#define SCAN_CH 1024
#define SCAN_NB ((N_NODES + SCAN_CH - 1) / SCAN_CH)   // 98

typedef __attribute__((ext_vector_type(8))) short short8;    // 8 bf16 = 4 VGPRs
typedef __attribute__((ext_vector_type(4))) float floatx4;

// ---- scalar load/store ----
__device__ __forceinline__ float ldf(const float* p) { return *p; }
__device__ __forceinline__ float ldf(const __hip_bfloat16* p) { return __bfloat162float(*p); }
__device__ __forceinline__ void stf(float* p, float v) { *p = v; }
__device__ __forceinline__ void stf(__hip_bfloat16* p, float v) { *p = __float2bfloat16(v); }

// 4-wide bf16 load/store (8B)
__device__ __forceinline__ void load4(const __hip_bfloat16* p, float v[4]) {
    const uint2 q = *(const uint2*)p;
    v[0] = __uint_as_float(q.x << 16);
    v[1] = __uint_as_float(q.x & 0xffff0000u);
    v[2] = __uint_as_float(q.y << 16);
    v[3] = __uint_as_float(q.y & 0xffff0000u);
}
__device__ __forceinline__ void store4(__hip_bfloat16* p, const float v[4]) {
    __hip_bfloat16 b[4];
    b[0] = __float2bfloat16(v[0]); b[1] = __float2bfloat16(v[1]);
    b[2] = __float2bfloat16(v[2]); b[3] = __float2bfloat16(v[3]);
    *(uint2*)p = *(const uint2*)b;
}

// async global->LDS, 16B per lane; LDS dest = wave-uniform base + lane*16
__device__ __forceinline__ void gload_lds16(const short* g, short* lds) {
    __builtin_amdgcn_global_load_lds(
        reinterpret_cast<const __attribute__((address_space(1))) unsigned int*>(
            reinterpret_cast<uintptr_t>(g)),
        reinterpret_cast<__attribute__((address_space(3))) unsigned int*>(
            reinterpret_cast<uintptr_t>(lds)),
        16, 0, 0);
}

// defensive: any out-of-range index becomes 0 (wrong answer, not a fault)
__device__ __forceinline__ int clampi(int v, int n) { return ((unsigned)v < (unsigned)n) ? v : 0; }

// ---------------- utility ----------------

__global__ void zero_f32(float* p, int n) {
    int i = blockIdx.x * blockDim.x + threadIdx.x;
    if (i < n) p[i] = 0.0f;
}
__global__ void zero_i32(int* p, int n) {
    int i = blockIdx.x * blockDim.x + threadIdx.x;
    if (i < n) p[i] = 0;
}

// x (float4-wide) -> bf16
__global__ void cvt_x(const float4* __restrict__ x, __hip_bfloat16* __restrict__ xb, int n4) {
    int i = blockIdx.x * blockDim.x + threadIdx.x;
    if (i >= n4) return;
    float4 v = x[i];
    float a[4] = {v.x, v.y, v.z, v.w};
    store4(&xb[(size_t)i * 4], a);
}

// weights -> contiguous bf16 buffer (offsets fixed)
#define WOF_EMB 0
#define WOF_L0  32768
#define WOF_R0  98304
#define WOF_L1  163840
#define WOF_R1  229376
#define WOF_P1  294912
#define W_TOTAL 557056
__global__ void cvt_w(const float* __restrict__ w_emb, const float* __restrict__ wl0,
                      const float* __restrict__ wr0, const float* __restrict__ wl1,
                      const float* __restrict__ wr1, const float* __restrict__ wp1,
                      __hip_bfloat16* __restrict__ wb) {
    int i = blockIdx.x * blockDim.x + threadIdx.x;
    if (i >= W_TOTAL) return;
    float v;
    if      (i < WOF_L0) v = w_emb[i - WOF_EMB];
    else if (i < WOF_R0) v = wl0[i - WOF_L0];
    else if (i < WOF_L1) v = wr0[i - WOF_R0];
    else if (i < WOF_R1) v = wl1[i - WOF_L1];
    else if (i < WOF_P1) v = wr1[i - WOF_R1];
    else                 v = wp1[i - WOF_P1];
    wb[i] = __float2bfloat16(v);
}

// ---------------- CSR build ----------------

__global__ void count_deg(const int* __restrict__ dst, int* __restrict__ deg, int nE) {
    int e = blockIdx.x * blockDim.x + threadIdx.x;
    if (e < nE) atomicAdd(&deg[clampi(dst[e], N_NODES)], 1);
}

__global__ __launch_bounds__(256) void csr_block_sums(const int* __restrict__ deg, int* __restrict__ bsum) {
    __shared__ int red[256];
    int b = blockIdx.x, t = threadIdx.x;
    int s = 0;
    #pragma unroll
    for (int j = 0; j < 4; j++) {
        int i = b * SCAN_CH + t + j * 256;
        if (i < N_NODES) s += deg[i];
    }
    red[t] = s; __syncthreads();
    for (int o = 128; o > 0; o >>= 1) {
        if (t < o) red[t] += red[t + o];
        __syncthreads();
    }
    if (t == 0) bsum[b] = red[0];
}

__global__ __launch_bounds__(128) void csr_scan_partials(const int* __restrict__ bsum, int* __restrict__ bpre) {
    __shared__ int sc[128];
    int t = threadIdx.x;
    int v = (t < SCAN_NB) ? bsum[t] : 0;
    sc[t] = v; __syncthreads();
    for (int o = 1; o < 128; o <<= 1) {
        int x = (t >= o) ? sc[t - o] : 0;
        __syncthreads();
        sc[t] += x;
        __syncthreads();
    }
    if (t < SCAN_NB) bpre[t] = sc[t] - v;   // exclusive
}

__global__ __launch_bounds__(256) void csr_write_rowptr(const int* __restrict__ deg,
                                                        const int* __restrict__ bpre,
                                                        int* __restrict__ rowptr) {
    __shared__ int sc[256];
    int b = blockIdx.x, t = threadIdx.x;
    int base = bpre[b];
    int i0 = b * SCAN_CH + t * 4;
    int d[4];
    int s = 0;
    #pragma unroll
    for (int j = 0; j < 4; j++) {
        d[j] = (i0 + j < N_NODES) ? deg[i0 + j] : 0;
        s += d[j];
    }
    sc[t] = s; __syncthreads();
    for (int o = 1; o < 256; o <<= 1) {
        int x = (t >= o) ? sc[t - o] : 0;
        __syncthreads();
        sc[t] += x;
        __syncthreads();
    }
    int pre = base + sc[t] - s;
    #pragma unroll
    for (int j = 0; j < 4; j++) {
        if (i0 + j < N_NODES) rowptr[i0 + j] = pre;
        pre += d[j];
    }
}

__global__ void fill_buckets(const int* __restrict__ src, const int* __restrict__ dst,
                             int* __restrict__ rowptr, int* __restrict__ ebuf, int nE) {
    int e = blockIdx.x * blockDim.x + threadIdx.x;
    if (e >= nE) return;
    int d = clampi(dst[e], N_NODES);
    int pos = atomicAdd(&rowptr[d], 1);
    if (pos < nE) ebuf[pos] = clampi(src[e], N_NODES);
}

// DETERMINISM: fill_buckets slots edges in atomic arrival order (varies per run).
// Sorting each row makes summation order a pure function of the input multiset
// -> bit-exact output every call (required by the post-timing re-check; see R4).
__global__ void sort_rows(const int* __restrict__ rowend, const int* __restrict__ deg,
                          int* __restrict__ ebuf) {
    int n = blockIdx.x * blockDim.x + threadIdx.x;
    if (n >= N_NODES) return;
    int end = rowend[n];
    int start = end - deg[n];
    for (int i = start + 1; i < end; i++) {          // insertion sort (mean deg ~5)
        int key = ebuf[i];
        int j = i - 1;
        while (j >= start && ebuf[j] > key) { ebuf[j + 1] = ebuf[j]; j--; }
        ebuf[j + 1] = key;
    }
}

// ---------------- gather aggregation ----------------
// one wave per node: agg[n,:] = (sum_{s in in(n)} h[s,:] + h[n,:]) / (deg+1)

__global__ __launch_bounds__(256) void gather_agg(const __hip_bfloat16* __restrict__ h,
                                                  const int* __restrict__ rowend,
                                                  const int* __restrict__ deg,
                                                  const int* __restrict__ ebuf,
                                                  __hip_bfloat16* __restrict__ agg) {
    int wave = threadIdx.x >> 6, lane = threadIdx.x & 63;
    int n = blockIdx.x * 4 + wave;
    if (n >= N_NODES) return;
    int dg  = deg[n];
    int end = rowend[n];
    int start = end - dg;
    float acc[4];
    load4(&h[(long long)n * HID + lane * 4], acc);   // self loop
    for (int e = start; e < end; e++) {
        int s = ebuf[e];
        float v[4];
        load4(&h[(long long)s * HID + lane * 4], v);
        acc[0] += v[0]; acc[1] += v[1]; acc[2] += v[2]; acc[3] += v[3];
    }
    float inv = 1.0f / (float)(dg + 1);
    acc[0] *= inv; acc[1] *= inv; acc[2] *= inv; acc[3] *= inv;
    store4(&agg[(long long)n * HID + lane * 4], acc);
}

// ---------------- MFMA GEMM with LDS-staged B ----------------
// C[M,256] = (relu)( A1[M,K]@B1[256,K]^T (+ A2@B2^T) + bias )
// Block: 256 thr = 4 waves (2x2); block tile 128 rows x 256 cols.
// Wave tile: 64 rows x 128 cols = 4x8 tiles of 16x16 (acc 128 VGPR).
// B staged per 32-k chunk into LDS via global_load_lds (16B/lane), layout
// fragment-major [quad][col] x 16B -> ds_read_b128 is 2-way bank (free, m136).
// A read direct from global (16B/lane, L1-shared between col-waves).
// MFMA order per acc tile identical to R6 (k ascending, a1*b1 then a2*b2)
// -> bit-identical numerics.

template <bool DUAL, typename TC, bool RELU>
__global__ __launch_bounds__(256, 2) void mfma_gemm(const __hip_bfloat16* __restrict__ A1,
                                                    const __hip_bfloat16* __restrict__ A2,
                                                    const __hip_bfloat16* __restrict__ B1,
                                                    const __hip_bfloat16* __restrict__ B2,
                                                    const float* __restrict__ bias,
                                                    TC* __restrict__ C, int M, int K) {
    const int N = 256;
    __shared__ __align__(16) short Bs1[4 * 256 * 8];   // 16 KB
    __shared__ __align__(16) short Bs2[4 * 256 * 8];   // 16 KB
    int w = threadIdx.x >> 6, lane = threadIdx.x & 63;
    int quad = lane >> 4, l16 = lane & 15;
    int wr = w >> 1, wc = w & 1;
    int row0 = blockIdx.x * 128 + wr * 64;
    int colbase = wc * 128;

    const short* A1s = (const short*)A1;
    const short* A2s = (const short*)A2;
    const short* B1s = (const short*)B1;
    const short* B2s = (const short*)B2;

    floatx4 acc[4][8] = {};

    int r[4];
    #pragma unroll
    for (int i = 0; i < 4; i++) {
        int rr = row0 + i * 16 + l16;
        r[i] = rr < M ? rr : M - 1;          // clamped loads; stores guarded
    }
    int scol = w * 64 + lane;                // this thread's staging column

    for (int k0 = 0; k0 < K; k0 += 32) {
        __syncthreads();                     // previous stage's reads done before overwrite
        #pragma unroll
        for (int q = 0; q < 4; q++) {
            gload_lds16(B1s + (size_t)scol * K + k0 + q * 8, &Bs1[(q * 256 + w * 64) * 8]);
            if (DUAL)
                gload_lds16(B2s + (size_t)scol * K + k0 + q * 8, &Bs2[(q * 256 + w * 64) * 8]);
        }
        // A fragments: direct global, independent of LDS staging
        int ka = k0 + quad * 8;
        short8 a1[4], a2[4];
        #pragma unroll
        for (int i = 0; i < 4; i++) {
            a1[i] = *(const short8*)(A1s + (size_t)r[i] * K + ka);
            if (DUAL) a2[i] = *(const short8*)(A2s + (size_t)r[i] * K + ka);
        }
        __syncthreads();                     // staging drained (vmcnt(0) inserted by compiler)

        short8 b1[8], b2[8];
        #pragma unroll
        for (int ct = 0; ct < 8; ct++) {
            int col = colbase + ct * 16 + l16;
            b1[ct] = *(const short8*)&Bs1[(quad * 256 + col) * 8];
            if (DUAL) b2[ct] = *(const short8*)&Bs2[(quad * 256 + col) * 8];
        }
        #pragma unroll
        for (int i = 0; i < 4; i++) {
            #pragma unroll
            for (int ct = 0; ct < 8; ct++) {
                acc[i][ct] = __builtin_amdgcn_mfma_f32_16x16x32_bf16(a1[i], b1[ct], acc[i][ct], 0, 0, 0);
                if (DUAL)
                    acc[i][ct] = __builtin_amdgcn_mfma_f32_16x16x32_bf16(a2[i], b2[ct], acc[i][ct], 0, 0, 0);
            }
        }
    }

    #pragma unroll
    for (int rt = 0; rt < 4; rt++) {
        #pragma unroll
        for (int ct = 0; ct < 8; ct++) {
            int c = colbase + ct * 16 + l16;
            float bc = bias[c];
            #pragma unroll
            for (int i = 0; i < 4; i++) {
                int rr = row0 + rt * 16 + quad * 4 + i;
                if (rr < M) {
                    float v = acc[rt][ct][i] + bc;
                    if (RELU) v = fmaxf(v, 0.0f);
                    stf(&C[(size_t)rr * N + c], v);
                }
            }
        }
    }
}

// ---------------- prediction head ----------------

__global__ __launch_bounds__(256) void build_comb(const __hip_bfloat16* __restrict__ h,
                                                  const int* __restrict__ src_idx,
                                                  const int* __restrict__ dst_idx,
                                                  __hip_bfloat16* __restrict__ comb) {
    int row = blockIdx.x;
    int t = threadIdx.x;
    int s = clampi(src_idx[row], N_NODES);
    int d = clampi(dst_idx[row], N_NODES);
    float sv = ldf(&h[(long long)s * HID + t]);
    float dv = ldf(&h[(long long)d * HID + t]);
    __hip_bfloat16* cr = &comb[(long long)row * (4 * HID)];
    stf(&cr[t], sv);
    stf(&cr[HID + t], dv);
    stf(&cr[2 * HID + t], sv * dv);
    stf(&cr[3 * HID + t], fabsf(sv - dv));
}

__global__ __launch_bounds__(256) void pred_final(const float* __restrict__ hidden,
                                                  const float* __restrict__ wp2,
                                                  const float* __restrict__ bp2,
                                                  float* __restrict__ out) {
    int wave = threadIdx.x >> 6;
    int lane = threadIdx.x & 63;
    int row = blockIdx.x * 4 + wave;
    if (row >= N_LINKS) return;
    const float4 hv = *(const float4*)&hidden[(long long)row * HID + lane * 4];
    const float4 wv = *(const float4*)&wp2[lane * 4];
    float v = hv.x * wv.x + hv.y * wv.y + hv.z * wv.z + hv.w * wv.w;
    #pragma unroll
    for (int off = 32; off > 0; off >>= 1) v += __shfl_down(v, off, 64);
    if (lane == 0) out[row] = 1.0f / (1.0f + expf(-(v + bp2[0])));
}

// ---------------- launch ----------------

extern "C" void kernel_launch(void* const* d_in, const int* in_sizes, int n_in,
                              void* d_out, int out_size, void* d_ws, size_t ws_size,
                              hipStream_t stream) {
    const float* x          = (const float*)d_in[0];
    const int*   edge_index = (const int*)d_in[1];
    const int*   e_src      = edge_index;            // row 0
    const int*   e_dst      = edge_index + N_EDGES;  // row 1
    const int*   src_idx    = (const int*)d_in[3];
    const int*   dst_idx    = (const int*)d_in[4];
    const float* w_emb      = (const float*)d_in[5];
    const float* b_emb      = (const float*)d_in[6];
    const float* wl0        = (const float*)d_in[8];
    const float* bl0        = (const float*)d_in[9];
    const float* wr0        = (const float*)d_in[10];
    const float* wl1        = (const float*)d_in[13];
    const float* bl1        = (const float*)d_in[14];
    const float* wr1        = (const float*)d_in[15];
    const float* wp1        = (const float*)d_in[18];
    const float* bp1        = (const float*)d_in[19];
    const float* wp2        = (const float*)d_in[20];
    const float* bp2        = (const float*)d_in[21];
    float* out = (float*)d_out;

    typedef __hip_bfloat16 bf16;
    const size_t NH = (size_t)N_NODES * HID;

    // workspace plan (~183 MB; ws proven >= 205 MB by R2)
    char* p = (char*)d_ws;
    bf16* h0   = (bf16*)p;  p += NH * 2;                       // 51.2 MB
    bf16* h1   = (bf16*)p;  p += NH * 2;                       // 51.2 MB
    bf16* agg  = (bf16*)p;  p += NH * 2;                       // 51.2 MB
    bf16* xb   = (bf16*)p;  p += (size_t)N_NODES * FEAT * 2;   // 25.6 MB
    bf16* wb   = (bf16*)p;  p += (size_t)W_TOTAL * 2;          // 1.1 MB
    p = (char*)(((uintptr_t)p + 255) & ~(uintptr_t)255);
    int* deg    = (int*)p; p += (size_t)N_NODES * 4;
    int* rowptr = (int*)p; p += (size_t)N_NODES * 4;
    int* ebuf   = (int*)p; p += (size_t)N_EDGES * 4;
    int* bsum   = (int*)p; p += 128 * 4;
    int* bpre   = (int*)p; p += 128 * 4;
    const size_t need = (size_t)(p - (char*)d_ws);

    if (ws_size < need) {   // visible failure, no fault
        zero_f32<<<(out_size + 255) / 256, 256, 0, stream>>>(out, out_size);
        return;
    }

    // aliases (regions dead by the time they're reused):
    bf16*  comb   = agg;         // [16384][1024] bf16 = 33.6 MB <= 51.2
    float* hidden = (float*)h1;  // [16384][256] fp32 = 16.8 MB <= 51.2

    // ---- CSR build ----
    zero_i32<<<(N_NODES + 255) / 256, 256, 0, stream>>>(deg, N_NODES);
    count_deg<<<(N_EDGES + 255) / 256, 256, 0, stream>>>(e_dst, deg, N_EDGES);
    csr_block_sums<<<SCAN_NB, 256, 0, stream>>>(deg, bsum);
    csr_scan_partials<<<1, 128, 0, stream>>>(bsum, bpre);
    csr_write_rowptr<<<SCAN_NB, 256, 0, stream>>>(deg, bpre, rowptr);
    fill_buckets<<<(N_EDGES + 255) / 256, 256, 0, stream>>>(e_src, e_dst, rowptr, ebuf, N_EDGES);
    sort_rows<<<(N_NODES + 255) / 256, 256, 0, stream>>>(rowptr, deg, ebuf);
    // rowptr now holds row_end per node

    // ---- bf16 conversions ----
    cvt_x<<<((N_NODES * FEAT / 4) + 255) / 256, 256, 0, stream>>>((const float4*)x, xb, N_NODES * FEAT / 4);
    cvt_w<<<(W_TOTAL + 255) / 256, 256, 0, stream>>>(w_emb, wl0, wr0, wl1, wr1, wp1, wb);

    const int ggrid = (N_NODES + 127) / 128;   // 782

    // ---- embedding: h0 = xb @ w_emb^T + b_emb ----
    mfma_gemm<false, bf16, false><<<ggrid, 256, 0, stream>>>(
        xb, nullptr, wb + WOF_EMB, nullptr, b_emb, h0, N_NODES, FEAT);

    // ---- layer 0: h1 = relu(agg@wl0^T + bl0 + h0@wr0^T) ----
    gather_agg<<<(N_NODES + 3) / 4, 256, 0, stream>>>(h0, rowptr, deg, ebuf, agg);
    mfma_gemm<true, bf16, true><<<ggrid, 256, 0, stream>>>(
        agg, h0, wb + WOF_L0, wb + WOF_R0, bl0, h1, N_NODES, HID);

    // ---- layer 1: h0 = relu(agg@wl1^T + bl1 + h1@wr1^T) ----
    gather_agg<<<(N_NODES + 3) / 4, 256, 0, stream>>>(h1, rowptr, deg, ebuf, agg);
    mfma_gemm<true, bf16, true><<<ggrid, 256, 0, stream>>>(
        agg, h1, wb + WOF_L1, wb + WOF_R1, bl1, h0, N_NODES, HID);

    // ---- prediction head ----
    build_comb<<<N_LINKS, 256, 0, stream>>>(h0, src_idx, dst_idx, comb);
    mfma_gemm<false, float, true><<<(N_LINKS + 127) / 128, 256, 0, stream>>>(
        comb, nullptr, wb + WOF_P1, nullptr, bp1, hidden, N_LINKS, 4 * HID);
    pred_final<<<N_LINKS / 4, 256, 0, stream>>>(hidden, wp2, bp2, out);
}